// Round 1
// baseline (2928.244 us; speedup 1.0000x reference)
//
#include <hip/hip_runtime.h>
#include <hip/hip_bf16.h>

// B=4, H=W=256, QD=64, VD=256, NH=8, WS=8
// windows: 32x32 per image => 1024/image, 4096 total; tokens per window n=64
// ws layout (floats):
static constexpr size_t OFF_ATTN_OUT = 0;                  // [4096][256][64] = 67108864 floats (windowed attn output)
static constexpr size_t OFF_WQT = 67108864;                // [c][o] 64x64
static constexpr size_t OFF_WKT = OFF_WQT + 4096;          // 64x64
static constexpr size_t OFF_WVT = OFF_WKT + 4096;          // [c][o] 256x256
static constexpr size_t OFF_PWT = OFF_WVT + 65536;         // [c][o] 256x256
// total = 67248128 floats = 269 MB

__global__ __launch_bounds__(256) void k_transpose(const float* __restrict__ Wq,
    const float* __restrict__ Wk, const float* __restrict__ Wv,
    const float* __restrict__ pw, float* __restrict__ wsf) {
  int idx = blockIdx.x * 256 + threadIdx.x;   // 0..65535
  if (idx < 4096) {
    int c = idx >> 6, o = idx & 63;
    wsf[OFF_WQT + idx] = Wq[o * 64 + c];
    wsf[OFF_WKT + idx] = Wk[o * 64 + c];
  }
  {
    int c = idx >> 8, o = idx & 255;
    wsf[OFF_WVT + idx] = Wv[o * 256 + c];
    wsf[OFF_PWT + idx] = pw[o * 256 + c];
  }
}

// Fused: v-proj, q-proj, k-proj(of qp), QK^T + bias, softmax, PV.
// 512 threads = 8 waves. One block per window.
__global__ __launch_bounds__(512) void k_attn(const float* __restrict__ q,
    const float* __restrict__ v, const float* __restrict__ WqT,
    const float* __restrict__ WkT, const float* __restrict__ WvT,
    const float* __restrict__ bias_table, float* __restrict__ attn_out) {
  __shared__ float vps[16384];     // [o(256)][p(64)]   64 KB
  __shared__ float buf0[4096];     // v chunk / q window [c(64)][p(64)]  16 KB
  __shared__ float qps_s[4096];    // [o][p] 16 KB
  __shared__ float kps_s[4096];    // [o][p] 16 KB
  __shared__ float bias_s[1800];   // [225][8] 7.2 KB

  int t = threadIdx.x;
  int win = blockIdx.x;
  int b = win >> 10;
  int wy = (win >> 5) & 31, wx = win & 31;
  int h0 = wy * 8, w0 = wx * 8;
  int p = t & 63;                                    // token/pixel lane
  int og = __builtin_amdgcn_readfirstlane(t >> 6);   // wave id 0..7

  for (int i = t; i < 1800; i += 512) bias_s[i] = bias_table[i];

  // ---------- v-proj: vp[o][p] = sum_c Wv[o][c] * v[c][p], o = og*32+i ----------
  const float* vb = v + (size_t)b * 16777216;
  float vacc[32];
  #pragma unroll
  for (int i = 0; i < 32; ++i) vacc[i] = 0.f;
  for (int cc = 0; cc < 4; ++cc) {
    __syncthreads();  // previous chunk reads done before overwrite
    #pragma unroll
    for (int k = 0; k < 8; ++k) {
      int lin = k * 512 + t;
      int c = lin >> 6, pp = lin & 63;
      buf0[lin] = vb[(size_t)(cc * 64 + c) * 65536 + (size_t)(h0 + (pp >> 3)) * 256 + w0 + (pp & 7)];
    }
    __syncthreads();
    for (int c = 0; c < 64; ++c) {
      float xv = buf0[(c << 6) + p];
      const float* wr = WvT + (size_t)(cc * 64 + c) * 256 + og * 32;
      #pragma unroll
      for (int i = 0; i < 32; ++i) vacc[i] += wr[i] * xv;
    }
  }
  #pragma unroll
  for (int i = 0; i < 32; ++i) vps[(og * 32 + i) * 64 + p] = vacc[i];

  // ---------- q window load (reuse buf0) ----------
  __syncthreads();
  const float* qb = q + (size_t)b * 4194304;
  #pragma unroll
  for (int k = 0; k < 8; ++k) {
    int lin = k * 512 + t;
    int c = lin >> 6, pp = lin & 63;
    buf0[lin] = qb[(size_t)c * 65536 + (size_t)(h0 + (pp >> 3)) * 256 + w0 + (pp & 7)];
  }
  __syncthreads();
  // qp: o = og*8+i
  {
    float acc[8];
    #pragma unroll
    for (int i = 0; i < 8; ++i) acc[i] = 0.f;
    for (int c = 0; c < 64; ++c) {
      float xv = buf0[(c << 6) + p];
      const float* wr = WqT + (c << 6) + og * 8;
      #pragma unroll
      for (int i = 0; i < 8; ++i) acc[i] += wr[i] * xv;
    }
    #pragma unroll
    for (int i = 0; i < 8; ++i) qps_s[(og * 8 + i) * 64 + p] = acc[i];
  }
  __syncthreads();
  // kp = Wk @ qp
  {
    float acc[8];
    #pragma unroll
    for (int i = 0; i < 8; ++i) acc[i] = 0.f;
    for (int c = 0; c < 64; ++c) {
      float xv = qps_s[(c << 6) + p];
      const float* wr = WkT + (c << 6) + og * 8;
      #pragma unroll
      for (int i = 0; i < 8; ++i) acc[i] += wr[i] * xv;
    }
    #pragma unroll
    for (int i = 0; i < 8; ++i) kps_s[(og * 8 + i) * 64 + p] = acc[i];
  }
  __syncthreads();

  // ---------- dots + bias + softmax + PV ; row r = t => head h = og, token i = p ----------
  const float scale = 0.3535533905932738f;
  int h = og;
  int i = p;
  int yi = i >> 3, xi = i & 7;
  float qv[8];
  #pragma unroll
  for (int d = 0; d < 8; ++d) qv[d] = qps_s[(h * 8 + d) * 64 + i];
  float dots[64];
  #pragma unroll
  for (int j = 0; j < 64; ++j) dots[j] = 0.f;
  #pragma unroll
  for (int d = 0; d < 8; ++d) {
    float qd = qv[d];
    const float4* kr = (const float4*)(kps_s + (h * 8 + d) * 64);
    #pragma unroll
    for (int j4 = 0; j4 < 16; ++j4) {
      float4 x = kr[j4];
      dots[j4 * 4 + 0] += qd * x.x;
      dots[j4 * 4 + 1] += qd * x.y;
      dots[j4 * 4 + 2] += qd * x.z;
      dots[j4 * 4 + 3] += qd * x.w;
    }
  }
  int bbase = (yi * 15 + xi) * 8 + h;  // bias index base; per-j constant offset added below
  #pragma unroll
  for (int j = 0; j < 64; ++j) {
    int yj = j >> 3, xj = j & 7;
    int koff = ((7 - yj) * 15 + (7 - xj)) * 8;   // compile-time per unrolled j
    dots[j] = dots[j] * scale + bias_s[bbase + koff];
  }
  float m = dots[0];
  #pragma unroll
  for (int j = 1; j < 64; ++j) m = fmaxf(m, dots[j]);
  float sum = 0.f;
  #pragma unroll
  for (int j = 0; j < 64; ++j) { float e = __expf(dots[j] - m); dots[j] = e; sum += e; }
  float inv = 1.0f / sum;
  // PV: out[o=h*32+dv][i] = inv * sum_j dots[j] * vps[o][j]
  float* dstbase = attn_out + (size_t)win * 16384 + (size_t)(h * 32) * 64 + i;
  for (int dv = 0; dv < 32; ++dv) {
    const float4* vr = (const float4*)(vps + (h * 32 + dv) * 64);
    float acc = 0.f;
    #pragma unroll
    for (int j4 = 0; j4 < 16; ++j4) {
      float4 x = vr[j4];
      acc += dots[j4 * 4 + 0] * x.x + dots[j4 * 4 + 1] * x.y
           + dots[j4 * 4 + 2] * x.z + dots[j4 * 4 + 3] * x.w;
    }
    dstbase[dv * 64] = acc * inv;
  }
}

// Depthwise 8x8 conv (+reflect pad right/bottom by 1, zero pad 3) + BN(eval).
// Reads windowed layout [win][c][p], writes NCHW to d_out.
__global__ __launch_bounds__(256) void k_dwconv(const float* __restrict__ A,
    const float* __restrict__ dwk, const float* __restrict__ gamma,
    const float* __restrict__ beta, float* __restrict__ out) {
  __shared__ float in_s[39 * 40];
  __shared__ float k_s[64];
  __shared__ float beta_s;
  int t = threadIdx.x;
  int blk = blockIdx.x;          // ((b*256+c)*64 + tile)
  int tile = blk & 63;
  int bc = blk >> 6;
  int c = bc & 255;
  int b = bc >> 8;
  int ty = tile >> 3, tx = tile & 7;
  int y0 = ty * 32, x0 = tx * 32;
  if (t < 64) {
    float g = gamma[c] * rsqrtf(1.0f + 1e-5f);
    k_s[t] = dwk[c * 64 + t] * g;
  }
  if (t == 0) beta_s = beta[c];
  for (int lin = t; lin < 39 * 39; lin += 256) {
    int ul = lin / 39, vl = lin - ul * 39;
    int u = y0 - 3 + ul, vv = x0 - 3 + vl;
    float val = 0.f;
    if (u >= 0 && u <= 256 && vv >= 0 && vv <= 256) {
      int uu = (u == 256) ? 254 : u;        // reflect pad (edge excluded)
      int vm = (vv == 256) ? 254 : vv;
      int win = b * 1024 + (uu >> 3) * 32 + (vm >> 3);
      int pp = ((uu & 7) << 3) + (vm & 7);
      val = A[(size_t)win * 16384 + (size_t)c * 64 + pp];
    }
    in_s[ul * 40 + vl] = val;
  }
  __syncthreads();
  int x = t & 31;
  int yq = t >> 5;
  float bb = beta_s;
  for (int k = 0; k < 4; ++k) {
    int y = yq * 4 + k;
    float acc = 0.f;
    #pragma unroll
    for (int ky = 0; ky < 8; ++ky) {
      #pragma unroll
      for (int kx = 0; kx < 8; ++kx)
        acc += k_s[ky * 8 + kx] * in_s[(y + ky) * 40 + (x + kx)];
    }
    out[(size_t)(b * 256 + c) * 65536 + (size_t)(y0 + y) * 256 + x0 + x] = acc + bb;
  }
}

// Pointwise 256x256, in-place on d_out. 64 pixels per block.
__global__ __launch_bounds__(256) void k_pw(const float* __restrict__ pwT, float* out) {
  __shared__ float X_s[16384];    // [c(256)][p(64)] 64 KB
  int t = threadIdx.x;
  int bb = blockIdx.x;            // 4096 blocks
  int b = bb >> 10;
  int pp = (bb & 1023) << 6;
  size_t base = (size_t)b * 16777216 + pp;
  #pragma unroll 4
  for (int k = 0; k < 64; ++k) {
    int lin = k * 256 + t;
    int c = lin >> 6, p2 = lin & 63;
    X_s[lin] = out[base + (size_t)c * 65536 + p2];
  }
  __syncthreads();
  int p = t & 63;
  int og = __builtin_amdgcn_readfirstlane(t >> 6);
  float acc[64];
  #pragma unroll
  for (int i = 0; i < 64; ++i) acc[i] = 0.f;
  for (int c = 0; c < 256; ++c) {
    float xv = X_s[(c << 6) + p];
    const float* wr = pwT + (size_t)c * 256 + (og << 6);
    #pragma unroll
    for (int i = 0; i < 64; ++i) acc[i] += wr[i] * xv;
  }
  #pragma unroll
  for (int i = 0; i < 64; ++i) {
    int o = (og << 6) + i;
    out[base + (size_t)o * 65536 + p] = acc[i];
  }
}

extern "C" void kernel_launch(void* const* d_in, const int* in_sizes, int n_in,
                              void* d_out, int out_size, void* d_ws, size_t ws_size,
                              hipStream_t stream) {
  const float* q          = (const float*)d_in[0];
  const float* v          = (const float*)d_in[1];
  const float* Wq         = (const float*)d_in[2];
  const float* Wk         = (const float*)d_in[3];
  const float* Wv         = (const float*)d_in[4];
  const float* bias_table = (const float*)d_in[5];
  const float* dwk        = (const float*)d_in[6];
  const float* gamma      = (const float*)d_in[7];
  const float* beta       = (const float*)d_in[8];
  const float* pw         = (const float*)d_in[9];
  float* out = (float*)d_out;
  float* wsf = (float*)d_ws;

  k_transpose<<<256, 256, 0, stream>>>(Wq, Wk, Wv, pw, wsf);
  k_attn<<<4096, 512, 0, stream>>>(q, v, wsf + OFF_WQT, wsf + OFF_WKT,
                                   wsf + OFF_WVT, bias_table, wsf + OFF_ATTN_OUT);
  k_dwconv<<<65536, 256, 0, stream>>>(wsf + OFF_ATTN_OUT, dwk, gamma, beta, out);
  k_pw<<<4096, 256, 0, stream>>>(wsf + OFF_PWT, out);
}

// Round 3
// 2194.658 us; speedup vs baseline: 1.3343x; 1.3343x over previous
//
#include <hip/hip_runtime.h>
#include <hip/hip_bf16.h>

// B=4, H=W=256, QD=64, VD=256, NH=8, WS=8; 4096 windows of 64 tokens.
// ws layout (float offsets):
//   [0 .. 33554432)          vps bf16 windowed [4096][256][64]  (later reused for dw-out bf16 NCHW)
//   [33554432 .. 67108864)   attn-out bf16 windowed [4096][256][64]
//   [67108864 .. +32768)     Wv frag-linear bf16 (65536 ushorts)
//   next 32768               pw frag-linear bf16
//   next 4096                WqT f32 [c][o]
//   next 4096                WkT f32 [c][o]
static constexpr size_t OFF_VPS  = 0;
static constexpr size_t OFF_ATTN = 33554432;
static constexpr size_t OFF_DW   = 0;            // reuses vps region (vps dead after attn)
static constexpr size_t OFF_WVF  = 67108864;
static constexpr size_t OFF_PWF  = OFF_WVF + 32768;
static constexpr size_t OFF_WQT  = OFF_PWF + 32768;
static constexpr size_t OFF_WKT  = OFF_WQT + 4096;

typedef __attribute__((ext_vector_type(8))) short short8v;
typedef __attribute__((ext_vector_type(4))) float f32x4;
typedef __attribute__((ext_vector_type(4))) unsigned short ushort4v;

__device__ __forceinline__ unsigned short f2bf(float f) {
  unsigned int u = __builtin_bit_cast(unsigned int, f);
  u = u + 0x7fffu + ((u >> 16) & 1u);            // RNE
  return (unsigned short)(u >> 16);
}
__device__ __forceinline__ float bf2f(unsigned short h) {
  unsigned int u = ((unsigned int)h) << 16;
  return __builtin_bit_cast(float, u);
}

// ---------------- prep: frag-linear bf16 weights + transposed f32 Wq/Wk ----------------
__global__ __launch_bounds__(256) void k_prep(const float* __restrict__ Wq,
    const float* __restrict__ Wk, const float* __restrict__ Wv,
    const float* __restrict__ pwk, float* __restrict__ wsf) {
  int idx = blockIdx.x * 256 + threadIdx.x;      // 0..65535
  int j  = idx & 7;
  int l  = (idx >> 3) & 63;
  int mi = (idx >> 9) & 3;
  int ks = (idx >> 11) & 1;
  int wm = (idx >> 12) & 3;
  int kk = idx >> 14;
  int o = wm * 64 + mi * 16 + (l & 15);
  int c = kk * 64 + ks * 32 + (l >> 4) * 8 + j;
  unsigned short* wvf = (unsigned short*)(wsf + OFF_WVF);
  unsigned short* pwf = (unsigned short*)(wsf + OFF_PWF);
  wvf[idx] = f2bf(Wv[o * 256 + c]);
  pwf[idx] = f2bf(pwk[o * 256 + c]);
  if (idx < 4096) {
    int cc = idx >> 6, oo = idx & 63;
    wsf[OFF_WQT + idx] = Wq[oo * 64 + cc];
    wsf[OFF_WKT + idx] = Wk[oo * 64 + cc];
  }
}

// ---------------- v-proj MFMA GEMM: vp[o][pix] = sum_c Wv[o][c] v[c][pix] ----------------
// Block: 2 windows (128 px) x all 256 out channels. 8 waves as 4(M) x 2(N).
__global__ __launch_bounds__(512, 4) void k_vproj(const float* __restrict__ v,
    const ushort* __restrict__ Af, ushort* __restrict__ vps) {
  __shared__ ushort Bs[8192];                    // [lp(128)][k(64)] bf16, XOR-swizzled, 16 KB
  int t = threadIdx.x;
  int blk = blockIdx.x;                          // b*512 + wy*16 + wxp
  int wxp = blk & 15, wy = (blk >> 4) & 31, b = blk >> 9;
  int win0 = b * 1024 + wy * 32 + wxp * 2;
  int wid = __builtin_amdgcn_readfirstlane(t >> 6);
  int l = t & 63;
  int wn = wid & 1, wm = wid >> 1;
  int lp_s = t & 127;                            // staged pixel column
  int ci = t >> 7;                               // 0..3
  const float* src_base = v + (size_t)b * 16777216
      + (size_t)(wy * 8 + (lp_s >> 4)) * 256 + wxp * 16 + (lp_s & 15);

  f32x4 acc[4][4];
  #pragma unroll
  for (int mi = 0; mi < 4; ++mi)
    #pragma unroll
    for (int ni = 0; ni < 4; ++ni) acc[mi][ni] = (f32x4){0.f, 0.f, 0.f, 0.f};

  for (int kk = 0; kk < 4; ++kk) {
    __syncthreads();
    #pragma unroll
    for (int i0 = 0; i0 < 4; ++i0) {
      int cl = ci * 16 + i0 * 4;
      ushort4v u4;
      #pragma unroll
      for (int i = 0; i < 4; ++i)
        u4[i] = f2bf(src_base[(size_t)(kk * 64 + cl + i) * 65536]);
      int idx = (lp_s * 64 + cl) ^ ((lp_s & 7) << 3);
      *(ushort4v*)&Bs[idx] = u4;
    }
    __syncthreads();
    #pragma unroll
    for (int ks = 0; ks < 2; ++ks) {
      short8v bfrag[4];
      #pragma unroll
      for (int ni = 0; ni < 4; ++ni) {
        int lp = wn * 64 + ni * 16 + (l & 15);
        int k0 = ks * 32 + (l >> 4) * 8;
        int idx = (lp * 64 + k0) ^ ((lp & 7) << 3);
        bfrag[ni] = *(const short8v*)&Bs[idx];
      }
      #pragma unroll
      for (int mi = 0; mi < 4; ++mi) {
        short8v af = *(const short8v*)&Af[(size_t)((((kk * 4 + wm) * 2 + ks) * 4 + mi) * 64 + l) * 8];
        #pragma unroll
        for (int ni = 0; ni < 4; ++ni)
          acc[mi][ni] = __builtin_amdgcn_mfma_f32_16x16x32_bf16(af, bfrag[ni], acc[mi][ni], 0, 0, 0);
      }
    }
  }
  // C write: bf16 windowed [win][o][p]
  int cx = l & 15;
  int winw = win0 + (cx >> 3);
  int pxl = cx & 7;
  #pragma unroll
  for (int ni = 0; ni < 4; ++ni) {
    int r = wn * 4 + ni;
    int p = r * 8 + pxl;
    ushort* dst = vps + (size_t)winw * 16384 + p;
    #pragma unroll
    for (int mi = 0; mi < 4; ++mi) {
      int obase = wm * 64 + mi * 16 + (l >> 4) * 4;
      #pragma unroll
      for (int rr = 0; rr < 4; ++rr)
        dst[(obase + rr) * 64] = f2bf(acc[mi][ni][rr]);
    }
  }
}

// ---------------- fused qk-proj + window attention ----------------
__global__ __launch_bounds__(512, 4) void k_attn2(const float* __restrict__ q,
    const ushort* __restrict__ vps_g, const float* __restrict__ WqT,
    const float* __restrict__ WkT, const float* __restrict__ bias_table,
    ushort* __restrict__ attn_out) {
  __shared__ float buf0[4096];     // q, then kp   16 KB
  __shared__ float qps_s[4096];    // qp           16 KB
  __shared__ ushort vps_s[16384];  // [o][j] bf16  32 KB
  __shared__ float bias_s[1800];   // 7.2 KB

  int t = threadIdx.x;
  int win = blockIdx.x;
  int b = win >> 10;
  int wy = (win >> 5) & 31, wx = win & 31;
  int h0 = wy * 8, w0 = wx * 8;
  int p = t & 63;
  int og = __builtin_amdgcn_readfirstlane(t >> 6);

  // vps global -> LDS (contiguous 32 KB)
  {
    const uint4* vsrc = (const uint4*)(vps_g + (size_t)win * 16384);
    uint4* vdst = (uint4*)vps_s;
    #pragma unroll
    for (int i = 0; i < 4; ++i) vdst[i * 512 + t] = vsrc[i * 512 + t];
  }
  for (int i = t; i < 1800; i += 512) bias_s[i] = bias_table[i];

  // q window -> buf0
  const float* qb = q + (size_t)b * 4194304;
  #pragma unroll
  for (int k = 0; k < 8; ++k) {
    int lin = k * 512 + t;
    int c = lin >> 6, pp = lin & 63;
    buf0[lin] = qb[(size_t)c * 65536 + (size_t)(h0 + (pp >> 3)) * 256 + w0 + (pp & 7)];
  }
  __syncthreads();
  // qp
  {
    float acc[8];
    #pragma unroll
    for (int i = 0; i < 8; ++i) acc[i] = 0.f;
    for (int c = 0; c < 64; ++c) {
      float xv = buf0[(c << 6) + p];
      const float* wr = WqT + (c << 6) + og * 8;
      #pragma unroll
      for (int i = 0; i < 8; ++i) acc[i] += wr[i] * xv;
    }
    #pragma unroll
    for (int i = 0; i < 8; ++i) qps_s[(og * 8 + i) * 64 + p] = acc[i];
  }
  __syncthreads();
  // kp = Wk @ qp -> buf0
  {
    float acc[8];
    #pragma unroll
    for (int i = 0; i < 8; ++i) acc[i] = 0.f;
    for (int c = 0; c < 64; ++c) {
      float xv = qps_s[(c << 6) + p];
      const float* wr = WkT + (c << 6) + og * 8;
      #pragma unroll
      for (int i = 0; i < 8; ++i) acc[i] += wr[i] * xv;
    }
    __syncthreads();   // all qp reads done before overwriting buf0
    #pragma unroll
    for (int i = 0; i < 8; ++i) buf0[(og * 8 + i) * 64 + p] = acc[i];
  }
  __syncthreads();

  // dots + bias + softmax, row = (head og, token p)
  const float scale = 0.3535533905932738f;
  int h = og;
  int i = p;
  int yi = i >> 3, xi = i & 7;
  float qv[8];
  #pragma unroll
  for (int d = 0; d < 8; ++d) qv[d] = qps_s[(h * 8 + d) * 64 + i];
  float dots[64];
  #pragma unroll
  for (int j = 0; j < 64; ++j) dots[j] = 0.f;
  #pragma unroll
  for (int d = 0; d < 8; ++d) {
    float qd = qv[d];
    const float4* kr = (const float4*)(buf0 + (h * 8 + d) * 64);
    #pragma unroll
    for (int j4 = 0; j4 < 16; ++j4) {
      float4 x = kr[j4];
      dots[j4 * 4 + 0] += qd * x.x;
      dots[j4 * 4 + 1] += qd * x.y;
      dots[j4 * 4 + 2] += qd * x.z;
      dots[j4 * 4 + 3] += qd * x.w;
    }
  }
  int bbase = (yi * 15 + xi) * 8 + h;
  #pragma unroll
  for (int j = 0; j < 64; ++j) {
    int yj = j >> 3, xj = j & 7;
    int koff = ((7 - yj) * 15 + (7 - xj)) * 8;
    dots[j] = dots[j] * scale + bias_s[bbase + koff];
  }
  float m = dots[0];
  #pragma unroll
  for (int j = 1; j < 64; ++j) m = fmaxf(m, dots[j]);
  float sum = 0.f;
  #pragma unroll
  for (int j = 0; j < 64; ++j) { float e = __expf(dots[j] - m); dots[j] = e; sum += e; }
  float inv = 1.0f / sum;

  // PV from bf16 LDS rows (broadcast reads)
  ushort* dstbase = attn_out + (size_t)win * 16384 + (size_t)(h * 32) * 64 + i;
  for (int dv = 0; dv < 32; ++dv) {
    const uint4* vr = (const uint4*)(vps_s + (h * 32 + dv) * 64);
    float acc0 = 0.f, acc1 = 0.f;
    #pragma unroll
    for (int q4 = 0; q4 < 8; ++q4) {
      uint4 u = vr[q4];
      #pragma unroll
      for (int e = 0; e < 4; ++e) {
        unsigned int w = (&u.x)[e];
        float vlo = __builtin_bit_cast(float, w << 16);
        float vhi = __builtin_bit_cast(float, w & 0xffff0000u);
        int jj = q4 * 8 + e * 2;
        acc0 += dots[jj] * vlo;
        acc1 += dots[jj + 1] * vhi;
      }
    }
    dstbase[dv * 64] = f2bf((acc0 + acc1) * inv);
  }
}

// ---------------- depthwise 8x8 + BN: windowed bf16 in -> NCHW bf16 out ----------------
__global__ __launch_bounds__(256) void k_dwconv2(const ushort* __restrict__ A,
    const float* __restrict__ dwk, const float* __restrict__ gamma,
    const float* __restrict__ beta, ushort* __restrict__ outb) {
  __shared__ float in_s[71 * 72];   // 20.4 KB
  __shared__ float k_s[64];
  __shared__ float beta_s;
  int t = threadIdx.x;
  int blk = blockIdx.x;             // ((b*256+c)*16 + tile)
  int tile = blk & 15;
  int bc = blk >> 4;
  int c = bc & 255;
  int b = bc >> 8;
  int ty = tile >> 2, tx = tile & 3;
  int y0 = ty * 64, x0 = tx * 64;
  if (t < 64) k_s[t] = dwk[c * 64 + t] * (gamma[c] * rsqrtf(1.0f + 1e-5f));
  if (t == 0) beta_s = beta[c];
  for (int lin = t; lin < 71 * 71; lin += 256) {
    int ul = lin / 71, vl = lin - ul * 71;
    int u = y0 - 3 + ul, vv = x0 - 3 + vl;
    float val = 0.f;
    if (u >= 0 && u <= 256 && vv >= 0 && vv <= 256) {
      int uu = (u == 256) ? 254 : u;
      int vm = (vv == 256) ? 254 : vv;
      int w = b * 1024 + (uu >> 3) * 32 + (vm >> 3);
      int pp = ((uu & 7) << 3) + (vm & 7);
      val = bf2f(A[(size_t)w * 16384 + c * 64 + pp]);
    }
    in_s[ul * 72 + vl] = val;
  }
  __syncthreads();
  int ox = t & 63;
  int oy0 = (t >> 6) * 16;
  float bb = beta_s;
  for (int k = 0; k < 16; ++k) {
    int oy = oy0 + k;
    float acc = bb;
    #pragma unroll
    for (int ky = 0; ky < 8; ++ky)
      #pragma unroll
      for (int kx = 0; kx < 8; ++kx)
        acc += k_s[ky * 8 + kx] * in_s[(oy + ky) * 72 + ox + kx];
    outb[(size_t)(b * 256 + c) * 65536 + (size_t)(y0 + oy) * 256 + x0 + ox] = f2bf(acc);
  }
}

// ---------------- pointwise MFMA GEMM: out = pw x dwout, f32 NCHW ----------------
__global__ __launch_bounds__(512, 4) void k_pw2(const ushort* __restrict__ X,
    const ushort* __restrict__ Af, float* __restrict__ out) {
  __shared__ ushort Bs[8192];
  int t = threadIdx.x;
  int blk = blockIdx.x;             // b*512 + pb
  int pb = blk & 511, b = blk >> 9;
  int wid = __builtin_amdgcn_readfirstlane(t >> 6);
  int l = t & 63;
  int wn = wid & 1, wm = wid >> 1;
  int lp_s = t & 127, ci = t >> 7;
  const ushort* src_base = X + (size_t)b * 16777216 + (size_t)pb * 128 + lp_s;

  f32x4 acc[4][4];
  #pragma unroll
  for (int mi = 0; mi < 4; ++mi)
    #pragma unroll
    for (int ni = 0; ni < 4; ++ni) acc[mi][ni] = (f32x4){0.f, 0.f, 0.f, 0.f};

  for (int kk = 0; kk < 4; ++kk) {
    __syncthreads();
    #pragma unroll
    for (int i0 = 0; i0 < 4; ++i0) {
      int cl = ci * 16 + i0 * 4;
      ushort4v u4;
      #pragma unroll
      for (int i = 0; i < 4; ++i)
        u4[i] = src_base[(size_t)(kk * 64 + cl + i) * 65536];
      int idx = (lp_s * 64 + cl) ^ ((lp_s & 7) << 3);
      *(ushort4v*)&Bs[idx] = u4;
    }
    __syncthreads();
    #pragma unroll
    for (int ks = 0; ks < 2; ++ks) {
      short8v bfrag[4];
      #pragma unroll
      for (int ni = 0; ni < 4; ++ni) {
        int lp = wn * 64 + ni * 16 + (l & 15);
        int k0 = ks * 32 + (l >> 4) * 8;
        int idx = (lp * 64 + k0) ^ ((lp & 7) << 3);
        bfrag[ni] = *(const short8v*)&Bs[idx];
      }
      #pragma unroll
      for (int mi = 0; mi < 4; ++mi) {
        short8v af = *(const short8v*)&Af[(size_t)((((kk * 4 + wm) * 2 + ks) * 4 + mi) * 64 + l) * 8];
        #pragma unroll
        for (int ni = 0; ni < 4; ++ni)
          acc[mi][ni] = __builtin_amdgcn_mfma_f32_16x16x32_bf16(af, bfrag[ni], acc[mi][ni], 0, 0, 0);
      }
    }
  }
  // C write: f32 NCHW
  #pragma unroll
  for (int mi = 0; mi < 4; ++mi) {
    int obase = wm * 64 + mi * 16 + (l >> 4) * 4;
    #pragma unroll
    for (int ni = 0; ni < 4; ++ni) {
      int px = wn * 64 + ni * 16 + (l & 15);
      float* dst = out + (size_t)(b * 256 + obase) * 65536 + (size_t)pb * 128 + px;
      #pragma unroll
      for (int rr = 0; rr < 4; ++rr)
        dst[(size_t)rr * 65536] = acc[mi][ni][rr];
    }
  }
}

extern "C" void kernel_launch(void* const* d_in, const int* in_sizes, int n_in,
                              void* d_out, int out_size, void* d_ws, size_t ws_size,
                              hipStream_t stream) {
  const float* q          = (const float*)d_in[0];
  const float* v          = (const float*)d_in[1];
  const float* Wq         = (const float*)d_in[2];
  const float* Wk         = (const float*)d_in[3];
  const float* Wv         = (const float*)d_in[4];
  const float* bias_table = (const float*)d_in[5];
  const float* dwk        = (const float*)d_in[6];
  const float* gamma      = (const float*)d_in[7];
  const float* beta       = (const float*)d_in[8];
  const float* pw         = (const float*)d_in[9];
  float* out = (float*)d_out;
  float* wsf = (float*)d_ws;

  ushort* vps   = (ushort*)(wsf + OFF_VPS);
  ushort* attn  = (ushort*)(wsf + OFF_ATTN);
  ushort* dwout = (ushort*)(wsf + OFF_DW);
  const ushort* wvf = (const ushort*)(wsf + OFF_WVF);
  const ushort* pwf = (const ushort*)(wsf + OFF_PWF);

  k_prep<<<256, 256, 0, stream>>>(Wq, Wk, Wv, pw, wsf);
  k_vproj<<<2048, 512, 0, stream>>>(v, wvf, vps);
  k_attn2<<<4096, 512, 0, stream>>>(q, vps, wsf + OFF_WQT, wsf + OFF_WKT, bias_table, attn);
  k_dwconv2<<<16384, 256, 0, stream>>>(attn, dwk, gamma, beta, dwout);
  k_pw2<<<2048, 512, 0, stream>>>(dwout, pwf, out);
}